// Round 12
// baseline (214.182 us; speedup 1.0000x reference)
//
#include <hip/hip_runtime.h>
#include <hip/hip_bf16.h>
#include <math.h>

// EquivariantGraphConv fused kernel for MI355X (gfx950).
// B=2, N=512, D=HID=OUT=128.
//
// Structure: edge MLP factorized -- h1 = aw_i + Bbuf_j + dist*wd (per-node
// precompute), and since there is no activation between the two edge GEMMs,
// c1 = s@M + bias2 with M = eW2@cW1 precomputed (bf16, transposed).
// Aggregation via column sums of s: Sum_j edge_hidden = (Sum_j s)@eW2 + 512*eb2.
// 2 launches: prew (precompute), main (edge loop + in-block epilogue).
//
// Round 11 -> 12: occupancy pinned at 2 blocks/CU in every config (launch
// bounds, waves_per_eu, LDS 21.5KB all no-ops on it). Disambiguating move
// that wins either way: ONE 512-thread block per node (8 waves, 128x128
// s-tile). If the pin is per-block -> 16 waves/CU (2x VALU throughput).
// And regardless: the whole cross-block combine (atomicAdds, done counter,
// RMW re-reads -- the +31us tax measured R7->R10) is deleted; the j=512
// reduction is block-local; barriers per node halve.
// Wave w owns row-strip (w>>2)*64, col-slice (w&3)*32 -> identical per-wave
// register layout (wfM 32 + acc 32 VGPRs) and MFMA count as before.

typedef float f32x4 __attribute__((ext_vector_type(4)));
typedef short short8 __attribute__((ext_vector_type(8)));

#define MFMA16(a, b, c) __builtin_amdgcn_mfma_f32_16x16x32_bf16((a), (b), (c), 0, 0, 0)

__device__ __forceinline__ short f2bf(float x) {
    __hip_bfloat16 h = __float2bfloat16(x);
    union { __hip_bfloat16 h; short s; } v; v.h = h;
    return v.s;
}
__device__ __forceinline__ float bf2f(short s) {
    union { unsigned u; float f; } v; v.u = ((unsigned)(unsigned short)s) << 16;
    return v.f;
}
__device__ __forceinline__ float silu_f(float x) {
    return x * __builtin_amdgcn_rcpf(1.0f + __expf(-x));
}

// XOR swizzle for [rows][128] bf16 LDS tiles (G4: break stride-256B conflicts).
__device__ __forceinline__ int swz(int row, int col) {
    int byte = (row << 8) | (col << 1);
    byte ^= (row & 7) << 4;
    return byte >> 1;  // bf16-element index
}

// ---------- fused precompute, grid 1089 x 256:
// blocks [0,1024): Abuf/Bbuf per node
// blocks [1024,1089): M = eW2@cW1 -> MbfT (bf16, transposed), bias2
__global__ void egnn_prew(const float* __restrict__ feat, const float* __restrict__ eW1,
                          const float* __restrict__ eb1,
                          const float* __restrict__ eW2, const float* __restrict__ cW1,
                          const float* __restrict__ eb2, const float* __restrict__ cb1,
                          float* __restrict__ Abuf, float* __restrict__ Bbuf,
                          unsigned short* __restrict__ MbfT, float* __restrict__ bias2ws) {
    const int bid = blockIdx.x;
    const int t = threadIdx.x;   // 256
    if (bid < 1024) {
        __shared__ float f[128];
        if (t < 128) f[t] = feat[bid * 128 + t];
        __syncthreads();
        const int col  = t & 127;
        const int half = t >> 7;
        const float* W = eW1 + (size_t)half * 128 * 128 + col;
        float acc = half ? 0.f : eb1[col];
        #pragma unroll 8
        for (int k = 0; k < 128; ++k) acc += f[k] * W[(size_t)k * 128];
        if (half == 0) Abuf[bid * 128 + col] = acc;
        else           Bbuf[bid * 128 + col] = acc;
    } else {
        const int idx = (bid - 1024) * 2 + (t >> 7);   // 0..129
        const int c = t & 127;
        if (idx < 128) {
            float acc = 0.f;
            #pragma unroll 8
            for (int h = 0; h < 128; ++h) acc += eW2[idx * 128 + h] * cW1[h * 128 + c];
            MbfT[c * 128 + idx] = (unsigned short)f2bf(acc);
        } else if (idx == 128) {
            float acc = cb1[c];
            #pragma unroll 8
            for (int h = 0; h < 128; ++h) acc += eb2[h] * cW1[h * 128 + c];
            bias2ws[c] = acc;
        }
    }
}

// ---------- main: one 512-thread block per node; 4 j-tiles of 128 each.
__global__ void __launch_bounds__(512) egnn_main(
    const float* __restrict__ features, const float* __restrict__ coords,
    const float* __restrict__ eW1, const float* __restrict__ eW2,
    const float* __restrict__ eb2,
    const float* __restrict__ nW1, const float* __restrict__ nb1,
    const float* __restrict__ nW2, const float* __restrict__ nb2,
    const float* __restrict__ cW2, const float* __restrict__ cb2,
    const float* __restrict__ Abuf, const float* __restrict__ Bbuf,
    const unsigned short* __restrict__ MbfT, const float* __restrict__ bias2ws,
    float* __restrict__ out_feat, float* __restrict__ out_coord)
{
    constexpr int Nn = 512;
    // se: 128x128 bf16 s-tile (32KB); aggred[32][128] f32 (16KB) aliases it
    // after the final Bar2. dynbuf holds cdp[2][3][128]+warr[2][4][128] in
    // the loop; tail part[4][128]+pfi[128] alias it after BarT0.
    __shared__ __align__(16) short se[128 * 128];           // 32 KB
    __shared__ __align__(16) float dynbuf[1792];            // 7 KB
    __shared__ float aw[128], wd[128];
    __shared__ float aggs[128], aggh[128], hbuf[128];
    __shared__ float cred[8][3];
    __shared__ float ci3[3];

    float (*cdp)[3][128]  = reinterpret_cast<float(*)[3][128]>(dynbuf);        // [2][3][128]
    float (*warr)[4][128] = reinterpret_cast<float(*)[4][128]>(dynbuf + 768);  // [2][4][128]
    float (*aggred)[128]  = reinterpret_cast<float(*)[128]>(se);               // [32][128]
    float (*part)[128]    = reinterpret_cast<float(*)[128]>(dynbuf);           // [4][128] tail
    float* pfi = dynbuf + 512;                                                 // 128 tail

    const int tid  = threadIdx.x;    // 512
    const int lane = tid & 63;
    const int wave = tid >> 6;       // 0..7
    const int node = blockIdx.x;     // b*512 + i
    const int b    = node >> 9;

    if (tid < 128) {
        aw[tid] = Abuf[node * 128 + tid];      // includes eb1
        wd[tid] = eW1[256 * 128 + tid];        // distance row of eW1
    }
    if (tid == 0) {
        ci3[0] = coords[node * 3 + 0];
        ci3[1] = coords[node * 3 + 1];
        ci3[2] = coords[node * 3 + 2];
    }

    // ---- per-wave geometry: row-strip r0, col-slice c0
    const int r0 = (wave >> 2) * 64;
    const int c0 = (wave & 3) * 32;
    const int cfrag = c0 + (lane & 15);
    const int koff  = (lane >> 4) * 8;

    // ---- M^T fragments: 8 x dwordx4 loads from bf16 MbfT (L2-resident)
    short8 wfM[2][4];
    #pragma unroll
    for (int n2 = 0; n2 < 2; ++n2)
        #pragma unroll
        for (int k = 0; k < 4; ++k)
            wfM[n2][k] = *(const short8*)&MbfT[(size_t)(cfrag + n2 * 16) * 128 + k * 32 + koff];
    __syncthreads();

    const float b2_0  = bias2ws[cfrag], b2_1 = bias2ws[cfrag + 16];
    const float cw2_0 = cW2[cfrag],     cw2_1 = cW2[cfrag + 16];
    const float cb2v  = cb2[0];
    const float cix = ci3[0], ciy = ci3[1], ciz = ci3[2];

    const int jr = tid >> 2, cb = (tid & 3) * 32;   // build mapping (rows 0..127)
    const int rg = tid >> 4, c8 = (tid & 15) * 8;   // agg mapping (row-groups 0..31)

    float ap[8];                        // per-thread agg col partials
    #pragma unroll
    for (int q = 0; q < 8; ++q) ap[q] = 0.f;
    float cax = 0.f, cay = 0.f, caz = 0.f;

    for (int t = 0; t < 4; ++t) {
        const int par = t & 1;
        // -- build: s = silu(aw + Bbuf_j + dist*wd) -> bf16 LDS (128 rows)
        {
            const int j = t * 128 + jr;
            const float dx = cix - coords[(b * Nn + j) * 3 + 0];
            const float dy = ciy - coords[(b * Nn + j) * 3 + 1];
            const float dz = ciz - coords[(b * Nn + j) * 3 + 2];
            const float dj = sqrtf(dx * dx + dy * dy + dz * dz + 1e-8f);
            if ((tid & 3) == 0) {
                cdp[par][0][jr] = dx; cdp[par][1][jr] = dy; cdp[par][2][jr] = dz;
            }
            const float* Bj = Bbuf + (size_t)(b * Nn + j) * 128 + cb;
            #pragma unroll
            for (int cc = 0; cc < 32; cc += 8) {
                f32x4 x0 = *(const f32x4*)(Bj + cc);
                f32x4 x1 = *(const f32x4*)(Bj + cc + 4);
                short8 v;
                #pragma unroll
                for (int r = 0; r < 4; ++r) {
                    const int c = cb + cc + r;
                    v[r] = f2bf(silu_f(aw[c] + x0[r] + dj * wd[c]));
                }
                #pragma unroll
                for (int r = 0; r < 4; ++r) {
                    const int c = cb + cc + 4 + r;
                    v[4 + r] = f2bf(silu_f(aw[c] + x1[r] + dj * wd[c]));
                }
                *(short8*)&se[swz(jr, cb + cc)] = v;
            }
        }
        __syncthreads();                                   // Bar1: tile ready

        // -- GEMM: c1 = s @ M + bias2 (wave: 64-row strip x 32-col slice)
        f32x4 acc[4][2];
        #pragma unroll
        for (int m = 0; m < 4; ++m) {
            acc[m][0] = (f32x4){b2_0, b2_0, b2_0, b2_0};
            acc[m][1] = (f32x4){b2_1, b2_1, b2_1, b2_1};
        }
        #pragma unroll
        for (int m = 0; m < 4; ++m)
            #pragma unroll
            for (int k = 0; k < 4; ++k) {
                short8 a = *(const short8*)&se[swz(r0 + m * 16 + (lane & 15), k * 32 + koff)];
                acc[m][0] = MFMA16(a, wfM[0][k], acc[m][0]);
                acc[m][1] = MFMA16(a, wfM[1][k], acc[m][1]);
            }

        // -- agg partials: rows rg*4..rg*4+3, cols c8..c8+7 (4 x ds_read_b128)
        #pragma unroll
        for (int r = 0; r < 4; ++r) {
            short8 v = *(const short8*)&se[swz(rg * 4 + r, c8)];
            #pragma unroll
            for (int q = 0; q < 8; ++q) ap[q] += bf2f(v[q]);
        }

        // -- coord weights: w = silu(c1) . cW2 (this wave's 32-col slice)
        #pragma unroll
        for (int m = 0; m < 4; ++m)
            #pragma unroll
            for (int reg = 0; reg < 4; ++reg) {
                float v = silu_f(acc[m][0][reg]) * cw2_0
                        + silu_f(acc[m][1][reg]) * cw2_1;
                v += __shfl_xor(v, 1); v += __shfl_xor(v, 2);
                v += __shfl_xor(v, 4); v += __shfl_xor(v, 8);
                if ((lane & 15) == 0)
                    warr[par][wave & 3][r0 + m * 16 + (lane >> 4) * 4 + reg] = v;
            }
        __syncthreads();                                   // Bar2: warr/cdp ready, se free

        // -- coord accumulation: wave w handles rows w*16..w*16+15
        if (lane < 16) {
            const int row = wave * 16 + lane;
            const float w = warr[par][0][row] + warr[par][1][row]
                          + warr[par][2][row] + warr[par][3][row] + cb2v;
            cax += w * cdp[par][0][row];
            cay += w * cdp[par][1][row];
            caz += w * cdp[par][2][row];
        }
    }

    // ---- flush agg partials (aggred aliases se) and per-wave coord sums
    #pragma unroll
    for (int q = 0; q < 8; ++q) aggred[rg][c8 + q] = ap[q];
    {
        float sx = cax, sy = cay, sz = caz;
        sx += __shfl_xor(sx, 1); sy += __shfl_xor(sy, 1); sz += __shfl_xor(sz, 1);
        sx += __shfl_xor(sx, 2); sy += __shfl_xor(sy, 2); sz += __shfl_xor(sz, 2);
        sx += __shfl_xor(sx, 4); sy += __shfl_xor(sy, 4); sz += __shfl_xor(sz, 4);
        sx += __shfl_xor(sx, 8); sy += __shfl_xor(sy, 8); sz += __shfl_xor(sz, 8);
        if (lane == 0) { cred[wave][0] = sx; cred[wave][1] = sy; cred[wave][2] = sz; }
    }
    __syncthreads();    // BarT0: aggred/cred ready; cdp/warr dead (tail may alias)

    const int c = tid & 127, g = tid >> 7;   // g uniform per wave-pair (0..3)
    if (tid < 128) {
        float s = 0.f;
        #pragma unroll
        for (int gg = 0; gg < 32; ++gg) s += aggred[gg][tid];
        aggs[tid] = s;
        pfi[tid]  = features[node * 128 + tid];
    }
    if (tid < 3) {
        float s = 0.f;
        #pragma unroll
        for (int w = 0; w < 8; ++w) s += cred[w][tid];
        out_coord[node * 3 + tid] = ci3[tid] + s * (1.f / 512.f);
    }
    __syncthreads();    // BarT1: aggs/pfi ready

    // ---- aggregated = (Sum_j s @ eW2)/512 + eb2, split-k over 4 groups
    {
        float a2 = 0.f;
        #pragma unroll 8
        for (int k = g * 32; k < g * 32 + 32; ++k) a2 += aggs[k] * eW2[k * 128 + c];
        if (g) part[g][c] = a2;
        __syncthreads();
        if (!g) aggh[c] = (a2 + part[1][c] + part[2][c] + part[3][c]) * (1.f / 512.f) + eb2[c];
        __syncthreads();   // BarT2: aggh ready; part free
    }
    // ---- node MLP layer 1: input [fi | aggh] (256), split over 4 groups
    {
        float a2 = (g == 0) ? nb1[c] : 0.f;
        if (g < 2) {
            #pragma unroll 8
            for (int k = g * 64; k < g * 64 + 64; ++k) a2 += pfi[k] * nW1[k * 128 + c];
        } else {
            #pragma unroll 8
            for (int k = (g - 2) * 64; k < (g - 2) * 64 + 64; ++k)
                a2 += aggh[k] * nW1[(128 + k) * 128 + c];
        }
        if (g) part[g][c] = a2;
        __syncthreads();
        if (!g) hbuf[c] = silu_f(a2 + part[1][c] + part[2][c] + part[3][c]);
        __syncthreads();   // hbuf ready; part free
    }
    // ---- node MLP layer 2, split-k over 4 groups
    {
        float a2 = (g == 0) ? nb2[c] : 0.f;
        #pragma unroll 8
        for (int k = g * 32; k < g * 32 + 32; ++k) a2 += hbuf[k] * nW2[k * 128 + c];
        if (g) part[g][c] = a2;
        __syncthreads();
        if (!g) out_feat[node * 128 + c] = a2 + part[1][c] + part[2][c] + part[3][c];
    }
}

extern "C" void kernel_launch(void* const* d_in, const int* in_sizes, int n_in,
                              void* d_out, int out_size, void* d_ws, size_t ws_size,
                              hipStream_t stream)
{
    const float* features = (const float*)d_in[0];
    const float* coords   = (const float*)d_in[1];
    const float* eW1 = (const float*)d_in[2];
    const float* eb1 = (const float*)d_in[3];
    const float* eW2 = (const float*)d_in[4];
    const float* eb2 = (const float*)d_in[5];
    const float* nW1 = (const float*)d_in[6];
    const float* nb1 = (const float*)d_in[7];
    const float* nW2 = (const float*)d_in[8];
    const float* nb2 = (const float*)d_in[9];
    const float* cW1 = (const float*)d_in[10];
    const float* cb1 = (const float*)d_in[11];
    const float* cW2 = (const float*)d_in[12];
    const float* cb2 = (const float*)d_in[13];

    float* out = (float*)d_out;
    float* out_feat  = out;                       // (2,512,128)
    float* out_coord = out + 2 * 512 * 128;       // (2,512,3)

    float* Abuf      = (float*)d_ws;                    // 131072 f32
    float* Bbuf      = Abuf + 2 * 512 * 128;            // 131072 f32
    unsigned short* MbfT = (unsigned short*)(Bbuf + 2 * 512 * 128);  // 16384 u16
    float* bias2ws   = (float*)(MbfT + 128 * 128);      // 128 f32

    egnn_prew<<<1089, 256, 0, stream>>>(features, eW1, eb1, eW2, cW1, eb2, cb1,
                                        Abuf, Bbuf, MbfT, bias2ws);
    egnn_main<<<1024, 512, 0, stream>>>(features, coords, eW1, eW2, eb2,
                                        nW1, nb1, nW2, nb2, cW2, cb2,
                                        Abuf, Bbuf, MbfT, bias2ws,
                                        out_feat, out_coord);
}

// Round 13
// 178.156 us; speedup vs baseline: 1.2022x; 1.2022x over previous
//
#include <hip/hip_runtime.h>
#include <hip/hip_bf16.h>
#include <math.h>

// EquivariantGraphConv fused kernel for MI355X (gfx950).
// B=2, N=512, D=HID=OUT=128.
//
// Structure: edge MLP factorized -- h1 = aw_i + Bbuf_j + dist*wd (per-node
// precompute), and since there is no activation between the two edge GEMMs,
// c1 = s@M + bias2 with M = eW2@cW1 precomputed (bf16, transposed).
// Aggregation via column sums of s: Sum_j edge_hidden = (Sum_j s)@eW2 + 512*eb2.
//
// Round 12 -> 13: resident waves pinned ~8/CU regardless of block shape
// (R12: 512-thr -> 1 block/CU, 138us, worse). Revert to 256-thr; grid 1024
// (one node per block, 8 tiles) with BLOCK-LOCAL epilogue -- no atomics, no
// partial buffers, no done counters, 2 plain launches. Latency levers:
//  (1) build reads aw/wd as f32x4 (b128) -- explicit LDS vectorization.
//  (2) coordw reduce: xor1/xor2 via DPP quad_perm (VALU pipe, 0xB1/0x4E),
//      xor4/xor8 via ds_swizzle -- LDS-pipe ops halved vs 4x __shfl_xor.
//  (3) warr single-buffer (Bar1 separates write-after-read); cdp parity kept.

typedef float f32x4 __attribute__((ext_vector_type(4)));
typedef short short8 __attribute__((ext_vector_type(8)));

#define MFMA16(a, b, c) __builtin_amdgcn_mfma_f32_16x16x32_bf16((a), (b), (c), 0, 0, 0)

__device__ __forceinline__ short f2bf(float x) {
    __hip_bfloat16 h = __float2bfloat16(x);
    union { __hip_bfloat16 h; short s; } v; v.h = h;
    return v.s;
}
__device__ __forceinline__ float bf2f(short s) {
    union { unsigned u; float f; } v; v.u = ((unsigned)(unsigned short)s) << 16;
    return v.f;
}
__device__ __forceinline__ float silu_f(float x) {
    return x * __builtin_amdgcn_rcpf(1.0f + __expf(-x));
}

// XOR swizzle for [rows][128] bf16 LDS tiles (G4: break stride-256B conflicts).
__device__ __forceinline__ int swz(int row, int col) {
    int byte = (row << 8) | (col << 1);
    byte ^= (row & 7) << 4;
    return byte >> 1;  // bf16-element index
}

// ---------- fused precompute, grid 1089 x 256:
// blocks [0,1024): Abuf/Bbuf per node
// blocks [1024,1089): M = eW2@cW1 -> MbfT (bf16, transposed), bias2
__global__ void egnn_prew(const float* __restrict__ feat, const float* __restrict__ eW1,
                          const float* __restrict__ eb1,
                          const float* __restrict__ eW2, const float* __restrict__ cW1,
                          const float* __restrict__ eb2, const float* __restrict__ cb1,
                          float* __restrict__ Abuf, float* __restrict__ Bbuf,
                          unsigned short* __restrict__ MbfT, float* __restrict__ bias2ws) {
    const int bid = blockIdx.x;
    const int t = threadIdx.x;   // 256
    if (bid < 1024) {
        __shared__ float f[128];
        if (t < 128) f[t] = feat[bid * 128 + t];
        __syncthreads();
        const int col  = t & 127;
        const int half = t >> 7;
        const float* W = eW1 + (size_t)half * 128 * 128 + col;
        float acc = half ? 0.f : eb1[col];
        #pragma unroll 8
        for (int k = 0; k < 128; ++k) acc += f[k] * W[(size_t)k * 128];
        if (half == 0) Abuf[bid * 128 + col] = acc;
        else           Bbuf[bid * 128 + col] = acc;
    } else {
        const int idx = (bid - 1024) * 2 + (t >> 7);   // 0..129
        const int c = t & 127;
        if (idx < 128) {
            float acc = 0.f;
            #pragma unroll 8
            for (int h = 0; h < 128; ++h) acc += eW2[idx * 128 + h] * cW1[h * 128 + c];
            MbfT[c * 128 + idx] = (unsigned short)f2bf(acc);
        } else if (idx == 128) {
            float acc = cb1[c];
            #pragma unroll 8
            for (int h = 0; h < 128; ++h) acc += eb2[h] * cW1[h * 128 + c];
            bias2ws[c] = acc;
        }
    }
}

// ---------- main+post: one 256-thread block per node; 8 j-tiles of 64;
// block-local aggregation and node epilogue (no cross-block traffic).
__global__ void __launch_bounds__(256, 2) egnn_mainpost(
    const float* __restrict__ features, const float* __restrict__ coords,
    const float* __restrict__ eW1, const float* __restrict__ eW2,
    const float* __restrict__ eb2,
    const float* __restrict__ nW1, const float* __restrict__ nb1,
    const float* __restrict__ nW2, const float* __restrict__ nb2,
    const float* __restrict__ cW2, const float* __restrict__ cb2,
    const float* __restrict__ Abuf, const float* __restrict__ Bbuf,
    const unsigned short* __restrict__ MbfT, const float* __restrict__ bias2ws,
    float* __restrict__ out_feat, float* __restrict__ out_coord)
{
    constexpr int Nn = 512;
    // se: 64x128 bf16 s-tile (16KB); aggred[16][128] f32 (8KB) aliases it
    // after the loop.
    __shared__ __align__(16) short se[64 * 128];            // 16 KB
    __shared__ float aw[128], wd[128], pfi[128];
    __shared__ float cdp[2][3][64];                         // parity (vs next build)
    __shared__ float warr[4][64];                           // single buffer (see Bar1)
    __shared__ float aggs[128], aggh[128], hbuf[128], part2[128];
    __shared__ float cred[4][3];
    __shared__ float ci3[3];

    float (*aggred)[128] = reinterpret_cast<float(*)[128]>(se);   // [16][128] tail

    const int tid  = threadIdx.x;    // 256
    const int lane = tid & 63;
    const int wave = tid >> 6;       // 0..3
    const int node = blockIdx.x;     // b*512 + i
    const int b    = node >> 9;

    if (tid < 128) {
        aw[tid]  = Abuf[node * 128 + tid];     // includes eb1
        wd[tid]  = eW1[256 * 128 + tid];       // distance row of eW1
        pfi[tid] = features[node * 128 + tid];
    }
    if (tid == 0) {
        ci3[0] = coords[node * 3 + 0];
        ci3[1] = coords[node * 3 + 1];
        ci3[2] = coords[node * 3 + 2];
    }

    // ---- M^T fragments: 8 x dwordx4 loads from bf16 MbfT (L2-resident)
    const int cfrag = wave * 32 + (lane & 15);
    const int koff  = (lane >> 4) * 8;
    short8 wfM[2][4];
    #pragma unroll
    for (int n2 = 0; n2 < 2; ++n2)
        #pragma unroll
        for (int k = 0; k < 4; ++k)
            wfM[n2][k] = *(const short8*)&MbfT[(size_t)(cfrag + n2 * 16) * 128 + k * 32 + koff];
    __syncthreads();

    const float b2_0  = bias2ws[cfrag], b2_1 = bias2ws[cfrag + 16];
    const float cw2_0 = cW2[cfrag],     cw2_1 = cW2[cfrag + 16];
    const float cb2v  = cb2[0];
    const float cix = ci3[0], ciy = ci3[1], ciz = ci3[2];

    const int jr = tid >> 2, cb = (tid & 3) * 32;   // build mapping
    const int rg = tid >> 4, c8 = (tid & 15) * 8;   // agg mapping

    float ap[8];                        // per-thread agg col partials
    #pragma unroll
    for (int q = 0; q < 8; ++q) ap[q] = 0.f;
    float cax = 0.f, cay = 0.f, caz = 0.f;

    for (int t = 0; t < 8; ++t) {
        const int par = t & 1;
        // -- build: s = silu(aw + Bbuf_j + dist*wd) -> bf16 LDS (b128 aw/wd reads)
        {
            const int j = t * 64 + jr;
            const float dx = cix - coords[(b * Nn + j) * 3 + 0];
            const float dy = ciy - coords[(b * Nn + j) * 3 + 1];
            const float dz = ciz - coords[(b * Nn + j) * 3 + 2];
            const float dj = sqrtf(dx * dx + dy * dy + dz * dz + 1e-8f);
            if ((tid & 3) == 0) {
                cdp[par][0][jr] = dx; cdp[par][1][jr] = dy; cdp[par][2][jr] = dz;
            }
            const float* Bj = Bbuf + (size_t)(b * Nn + j) * 128 + cb;
            #pragma unroll
            for (int cc = 0; cc < 32; cc += 8) {
                f32x4 x0 = *(const f32x4*)(Bj + cc);
                f32x4 x1 = *(const f32x4*)(Bj + cc + 4);
                f32x4 a0 = *(const f32x4*)&aw[cb + cc];
                f32x4 a1 = *(const f32x4*)&aw[cb + cc + 4];
                f32x4 w0 = *(const f32x4*)&wd[cb + cc];
                f32x4 w1 = *(const f32x4*)&wd[cb + cc + 4];
                short8 v;
                #pragma unroll
                for (int r = 0; r < 4; ++r) v[r]     = f2bf(silu_f(a0[r] + x0[r] + dj * w0[r]));
                #pragma unroll
                for (int r = 0; r < 4; ++r) v[4 + r] = f2bf(silu_f(a1[r] + x1[r] + dj * w1[r]));
                *(short8*)&se[swz(jr, cb + cc)] = v;
            }
        }
        __syncthreads();                                   // Bar1: tile ready

        // -- GEMM: c1 = s @ M + bias2 (acc init = bias2)
        f32x4 acc[4][2];
        #pragma unroll
        for (int m = 0; m < 4; ++m) {
            acc[m][0] = (f32x4){b2_0, b2_0, b2_0, b2_0};
            acc[m][1] = (f32x4){b2_1, b2_1, b2_1, b2_1};
        }
        #pragma unroll
        for (int m = 0; m < 4; ++m)
            #pragma unroll
            for (int k = 0; k < 4; ++k) {
                short8 a = *(const short8*)&se[swz(m * 16 + (lane & 15), k * 32 + koff)];
                acc[m][0] = MFMA16(a, wfM[0][k], acc[m][0]);
                acc[m][1] = MFMA16(a, wfM[1][k], acc[m][1]);
            }

        // -- agg partials: rows rg*4..rg*4+3, cols c8..c8+7 (4 x ds_read_b128)
        #pragma unroll
        for (int r = 0; r < 4; ++r) {
            short8 v = *(const short8*)&se[swz(rg * 4 + r, c8)];
            #pragma unroll
            for (int q = 0; q < 8; ++q) ap[q] += bf2f(v[q]);
        }

        // -- coord weights: w = silu(c1).cW2; 16-lane reduce via DPP(xor1,2)
        //    + ds_swizzle(xor4,8) -- half the LDS-pipe ops of 4x shfl_xor.
        #pragma unroll
        for (int m = 0; m < 4; ++m)
            #pragma unroll
            for (int reg = 0; reg < 4; ++reg) {
                float v = silu_f(acc[m][0][reg]) * cw2_0
                        + silu_f(acc[m][1][reg]) * cw2_1;
                union { float f; int i; } u, o;
                u.f = v; o.i = __builtin_amdgcn_mov_dpp(u.i, 0xB1, 0xF, 0xF, true); v += o.f; // xor1
                u.f = v; o.i = __builtin_amdgcn_mov_dpp(u.i, 0x4E, 0xF, 0xF, true); v += o.f; // xor2
                u.f = v; o.i = __builtin_amdgcn_ds_swizzle(u.i, 0x101F);            v += o.f; // xor4
                u.f = v; o.i = __builtin_amdgcn_ds_swizzle(u.i, 0x201F);            v += o.f; // xor8
                if ((lane & 15) == 0)
                    warr[wave][m * 16 + (lane >> 4) * 4 + reg] = v;
            }
        __syncthreads();                                   // Bar2: warr/cdp ready, se free

        // -- coord accumulation: wave w handles rows w*16..w*16+15.
        //    warr single-buffer: these reads finish before Bar1(t+1), and the
        //    next warr writes happen only after Bar1(t+1).
        if (lane < 16) {
            const int row = wave * 16 + lane;
            const float w = warr[0][row] + warr[1][row]
                          + warr[2][row] + warr[3][row] + cb2v;
            cax += w * cdp[par][0][row];
            cay += w * cdp[par][1][row];
            caz += w * cdp[par][2][row];
        }
    }

    // ---- flush agg partials (aggred aliases se -- dead after final Bar2)
    #pragma unroll
    for (int q = 0; q < 8; ++q) aggred[rg][c8 + q] = ap[q];
    {
        float sx = cax, sy = cay, sz = caz;
        sx += __shfl_xor(sx, 1); sy += __shfl_xor(sy, 1); sz += __shfl_xor(sz, 1);
        sx += __shfl_xor(sx, 2); sy += __shfl_xor(sy, 2); sz += __shfl_xor(sz, 2);
        sx += __shfl_xor(sx, 4); sy += __shfl_xor(sy, 4); sz += __shfl_xor(sz, 4);
        sx += __shfl_xor(sx, 8); sy += __shfl_xor(sy, 8); sz += __shfl_xor(sz, 8);
        if (lane == 0) { cred[wave][0] = sx; cred[wave][1] = sy; cred[wave][2] = sz; }
    }
    __syncthreads();   // BarT0: aggred/cred ready

    const int c = tid & 127, g = tid >> 7;   // g uniform per wave-pair (0/1)
    if (tid < 128) {
        float s = 0.f;
        #pragma unroll
        for (int gg = 0; gg < 16; ++gg) s += aggred[gg][tid];
        aggs[tid] = s;                         // Sum_j s[j][tid]
    }
    if (tid < 3) {
        out_coord[node * 3 + tid] = ci3[tid]
            + (cred[0][tid] + cred[1][tid] + cred[2][tid] + cred[3][tid]) * (1.f / 512.f);
    }
    __syncthreads();   // BarT1: aggs ready

    // ---- aggregated = (Sum_j s @ eW2)/512 + eb2, split-k over g
    {
        float a2 = 0.f;
        #pragma unroll 8
        for (int k = g * 64; k < g * 64 + 64; ++k) a2 += aggs[k] * eW2[k * 128 + c];
        if (g == 1) part2[c] = a2;
        __syncthreads();
        if (g == 0) aggh[c] = (a2 + part2[c]) * (1.f / 512.f) + eb2[c];
        __syncthreads();
    }
    // ---- node MLP layer 1: g=0 features-half, g=1 agg-half of nW1
    {
        float a2 = (g == 0) ? nb1[c] : 0.f;
        const float* src = (g == 0) ? pfi : aggh;
        const float* W = nW1 + (size_t)(g << 7) * 128 + c;
        #pragma unroll 8
        for (int k = 0; k < 128; ++k) a2 += src[k] * W[(size_t)k * 128];
        if (g == 1) part2[c] = a2;
        __syncthreads();
        if (g == 0) hbuf[c] = silu_f(a2 + part2[c]);
        __syncthreads();
    }
    // ---- node MLP layer 2, split-k over g
    {
        float a2 = (g == 0) ? nb2[c] : 0.f;
        #pragma unroll 8
        for (int k = g * 64; k < g * 64 + 64; ++k) a2 += hbuf[k] * nW2[k * 128 + c];
        if (g == 1) part2[c] = a2;
        __syncthreads();
        if (g == 0) out_feat[node * 128 + c] = a2 + part2[c];
    }
}

extern "C" void kernel_launch(void* const* d_in, const int* in_sizes, int n_in,
                              void* d_out, int out_size, void* d_ws, size_t ws_size,
                              hipStream_t stream)
{
    const float* features = (const float*)d_in[0];
    const float* coords   = (const float*)d_in[1];
    const float* eW1 = (const float*)d_in[2];
    const float* eb1 = (const float*)d_in[3];
    const float* eW2 = (const float*)d_in[4];
    const float* eb2 = (const float*)d_in[5];
    const float* nW1 = (const float*)d_in[6];
    const float* nb1 = (const float*)d_in[7];
    const float* nW2 = (const float*)d_in[8];
    const float* nb2 = (const float*)d_in[9];
    const float* cW1 = (const float*)d_in[10];
    const float* cb1 = (const float*)d_in[11];
    const float* cW2 = (const float*)d_in[12];
    const float* cb2 = (const float*)d_in[13];

    float* out = (float*)d_out;
    float* out_feat  = out;                       // (2,512,128)
    float* out_coord = out + 2 * 512 * 128;       // (2,512,3)

    float* Abuf      = (float*)d_ws;                    // 131072 f32
    float* Bbuf      = Abuf + 2 * 512 * 128;            // 131072 f32
    unsigned short* MbfT = (unsigned short*)(Bbuf + 2 * 512 * 128);  // 16384 u16
    float* bias2ws   = (float*)(MbfT + 128 * 128);      // 128 f32

    egnn_prew<<<1089, 256, 0, stream>>>(features, eW1, eb1, eW2, cW1, eb2, cb1,
                                        Abuf, Bbuf, MbfT, bias2ws);
    egnn_mainpost<<<1024, 256, 0, stream>>>(features, coords, eW1, eW2, eb2,
                                            nW1, nb1, nW2, nb2, cW2, cb2,
                                            Abuf, Bbuf, MbfT, bias2ws,
                                            out_feat, out_coord);
}